// Round 1
// baseline (87558.478 us; speedup 1.0000x reference)
//
#include <hip/hip_runtime.h>
#include <hip/hip_bf16.h>

// LSTM tagger: T=4096, V=50257, E=512, H=1024, TAGS=64
//
// Plan:
//   K1 prep:   bsum = b_ih + b_hh; zero h ping-pong buffer + flags.
//   K2 gemm:   x_proj[T][4H] = emb[sentence] @ W_ih^T + bsum   (fp32 tiled)
//   K3 scan:   persistent 256 WGs x 256 thr. WG g owns h[4g..4g+4).
//              W_hh slice lives in VGPRs (64 fp32/thread). Per step:
//              poll peer flags -> agent-load h (4KB) -> LDS -> dot ->
//              wave reduce -> activations -> agent-store h slice -> flag.
//   K4 out:    tag_space = hs @ W_out^T + b_out; log_softmax over 64 tags.

#define T_LEN 4096
#define HID   1024
#define G4H   4096
#define EMBD  512
#define NTAGS 64
#define NWG   256

__device__ __forceinline__ float fast_sig(float x) {
    return 1.f / (1.f + __expf(-x));
}
__device__ __forceinline__ float fast_tanh(float x) {
    x = fminf(15.f, fmaxf(-15.f, x));
    float e = __expf(2.f * x);
    return (e - 1.f) / (e + 1.f);
}

__global__ void prep_kernel(const float* __restrict__ b_ih, const float* __restrict__ b_hh,
                            float* __restrict__ bsum, float* __restrict__ hbuf,
                            int* __restrict__ flags) {
    int i = blockIdx.x * blockDim.x + threadIdx.x;
    int n = gridDim.x * blockDim.x;
    for (int k = i; k < G4H; k += n) bsum[k] = b_ih[k] + b_hh[k];
    for (int k = i; k < 2 * HID; k += n) hbuf[k] = 0.f;
    for (int k = i; k < NWG; k += n) flags[k] = 0;
}

// C[m,n] = sum_k emb[sent[m]][k] * W_ih[n][k] + bsum[n]; 64x64 tile per WG.
__global__ __launch_bounds__(256) void xproj_gemm(const int* __restrict__ sent,
                                                  const float* __restrict__ emb,
                                                  const float* __restrict__ W_ih,
                                                  const float* __restrict__ bsum,
                                                  float* __restrict__ xp) {
    __shared__ float As[32][68];  // [k][m], pad 68 keeps 16B align + banks spread
    __shared__ float Bs[32][68];  // [k][n]
    const int tid = threadIdx.x;
    const int bx = blockIdx.x;  // n tile
    const int by = blockIdx.y;  // m tile
    const int tx = tid & 15, ty = tid >> 4;
    const int mrow = tid >> 2;        // 0..63
    const int kq = (tid & 3) * 8;     // 0,8,16,24

    float acc[4][4];
#pragma unroll
    for (int r = 0; r < 4; r++)
#pragma unroll
        for (int c = 0; c < 4; c++) acc[r][c] = 0.f;

    const int sid = sent[by * 64 + mrow];
    const float* arow = emb + (size_t)sid * EMBD;
    const float* brow = W_ih + (size_t)(bx * 64 + mrow) * EMBD;

    for (int kk = 0; kk < EMBD; kk += 32) {
        float4 a0 = *(const float4*)(arow + kk + kq);
        float4 a1 = *(const float4*)(arow + kk + kq + 4);
        float4 b0 = *(const float4*)(brow + kk + kq);
        float4 b1 = *(const float4*)(brow + kk + kq + 4);
        __syncthreads();  // previous compute done before overwrite
        const float* ap0 = (const float*)&a0;
        const float* ap1 = (const float*)&a1;
        const float* bp0 = (const float*)&b0;
        const float* bp1 = (const float*)&b1;
#pragma unroll
        for (int r = 0; r < 4; r++) {
            As[kq + r][mrow] = ap0[r];
            As[kq + 4 + r][mrow] = ap1[r];
            Bs[kq + r][mrow] = bp0[r];
            Bs[kq + 4 + r][mrow] = bp1[r];
        }
        __syncthreads();
#pragma unroll
        for (int k = 0; k < 32; k++) {
            float4 av = *(const float4*)&As[k][ty * 4];
            float4 bv = *(const float4*)&Bs[k][tx * 4];
            const float* ar = (const float*)&av;
            const float* br = (const float*)&bv;
#pragma unroll
            for (int r = 0; r < 4; r++)
#pragma unroll
                for (int c = 0; c < 4; c++) acc[r][c] = fmaf(ar[r], br[c], acc[r][c]);
        }
    }
    const int crow = by * 64 + ty * 4;
    const int ccol = bx * 64 + tx * 4;
    float bs[4];
#pragma unroll
    for (int c = 0; c < 4; c++) bs[c] = bsum[ccol + c];
#pragma unroll
    for (int r = 0; r < 4; r++) {
        float4 v;
        v.x = acc[r][0] + bs[0];
        v.y = acc[r][1] + bs[1];
        v.z = acc[r][2] + bs[2];
        v.w = acc[r][3] + bs[3];
        *(float4*)&xp[(size_t)(crow + r) * G4H + ccol] = v;
    }
}

// Persistent recurrent scan. 256 WGs x 256 threads; WG g owns h[4g..4g+4).
// Wave w (of 4) owns entry j = 4g+w; lane l covers columns {k*64+l : k=0..15}.
__global__ __launch_bounds__(256, 1) void lstm_scan(const float* __restrict__ W_hh,
                                                    const float* __restrict__ xp,
                                                    float* __restrict__ hbuf,
                                                    int* __restrict__ flags,
                                                    float* __restrict__ hs) {
    __shared__ float h_lds[HID];
    const int tid = threadIdx.x;
    const int bg = blockIdx.x;  // 0..255
    const int w = tid >> 6;     // wave 0..3
    const int l = tid & 63;
    const int j = bg * 4 + w;   // owned h index

    // preload W_hh slice into registers: wreg[q][k] = W_hh[q*H + j][k*64 + l]
    float wreg[4][16];
#pragma unroll
    for (int q = 0; q < 4; q++) {
        const float* wr = W_hh + (size_t)(q * HID + j) * HID + l;
#pragma unroll
        for (int k = 0; k < 16; k++) wreg[q][k] = wr[k * 64];
    }

    float c = 0.f;
    for (int s = 1; s <= T_LEN; ++s) {
        const int t = s - 1;
        // prefetch x_proj row entries (independent of h -> hides under poll)
        float xp0 = xp[(size_t)t * G4H + 0 * HID + j];
        float xp1 = xp[(size_t)t * G4H + 1 * HID + j];
        float xp2 = xp[(size_t)t * G4H + 2 * HID + j];
        float xp3 = xp[(size_t)t * G4H + 3 * HID + j];

        if (w == 0) {
            const int need = s - 1;
            for (;;) {
                int f0 = __hip_atomic_load(&flags[4 * l + 0], __ATOMIC_ACQUIRE, __HIP_MEMORY_SCOPE_AGENT);
                int f1 = __hip_atomic_load(&flags[4 * l + 1], __ATOMIC_ACQUIRE, __HIP_MEMORY_SCOPE_AGENT);
                int f2 = __hip_atomic_load(&flags[4 * l + 2], __ATOMIC_ACQUIRE, __HIP_MEMORY_SCOPE_AGENT);
                int f3 = __hip_atomic_load(&flags[4 * l + 3], __ATOMIC_ACQUIRE, __HIP_MEMORY_SCOPE_AGENT);
                if (f0 >= need && f1 >= need && f2 >= need && f3 >= need) break;
            }
        }
        __syncthreads();  // B1: h_{s-1} globally visible

        const float* hb = hbuf + ((s - 1) & 1) * HID;
        float h0 = __hip_atomic_load(&hb[tid + 0 * 256], __ATOMIC_RELAXED, __HIP_MEMORY_SCOPE_AGENT);
        float h1 = __hip_atomic_load(&hb[tid + 1 * 256], __ATOMIC_RELAXED, __HIP_MEMORY_SCOPE_AGENT);
        float h2 = __hip_atomic_load(&hb[tid + 2 * 256], __ATOMIC_RELAXED, __HIP_MEMORY_SCOPE_AGENT);
        float h3 = __hip_atomic_load(&hb[tid + 3 * 256], __ATOMIC_RELAXED, __HIP_MEMORY_SCOPE_AGENT);
        h_lds[tid + 0 * 256] = h0;
        h_lds[tid + 1 * 256] = h1;
        h_lds[tid + 2 * 256] = h2;
        h_lds[tid + 3 * 256] = h3;
        __syncthreads();  // B2: h staged in LDS

        float a0 = 0.f, a1 = 0.f, a2 = 0.f, a3 = 0.f;
#pragma unroll
        for (int k = 0; k < 16; k++) {
            float hv = h_lds[k * 64 + l];
            a0 = fmaf(wreg[0][k], hv, a0);
            a1 = fmaf(wreg[1][k], hv, a1);
            a2 = fmaf(wreg[2][k], hv, a2);
            a3 = fmaf(wreg[3][k], hv, a3);
        }
#pragma unroll
        for (int m = 32; m >= 1; m >>= 1) {
            a0 += __shfl_xor(a0, m);
            a1 += __shfl_xor(a1, m);
            a2 += __shfl_xor(a2, m);
            a3 += __shfl_xor(a3, m);
        }
        float gi = a0 + xp0, gf = a1 + xp1, gg = a2 + xp2, go = a3 + xp3;
        float si = fast_sig(gi);
        float sf = fast_sig(gf);
        float tg = fast_tanh(gg);
        float so = fast_sig(go);
        c = sf * c + si * tg;
        float hval = so * fast_tanh(c);

        if (l == 0) {
            __hip_atomic_store(&hbuf[(s & 1) * HID + j], hval, __ATOMIC_RELAXED, __HIP_MEMORY_SCOPE_AGENT);
            hs[(size_t)t * HID + j] = hval;
        }
        __syncthreads();  // B3: drains all 4 waves' h stores (vmcnt)
        if (tid == 0)
            __hip_atomic_store(&flags[bg], s, __ATOMIC_RELEASE, __HIP_MEMORY_SCOPE_AGENT);
    }
}

// tag_space = hs @ W_out^T + b_out; log_softmax per row. 8 rows per WG, 1 wave.
__global__ __launch_bounds__(64) void out_kernel(const float* __restrict__ hs,
                                                 const float* __restrict__ W_out,
                                                 const float* __restrict__ b_out,
                                                 float* __restrict__ out) {
    __shared__ float hl[8 * HID];
    const int l = threadIdx.x;
    const int b = blockIdx.x;  // 512 blocks
    const float* hr = hs + (size_t)b * 8 * HID;
#pragma unroll
    for (int jj = 0; jj < 32; jj++) {
        int f4 = l + 64 * jj;
        ((float4*)hl)[f4] = ((const float4*)hr)[f4];
    }
    __syncthreads();
    float acc[8];
#pragma unroll
    for (int r = 0; r < 8; r++) acc[r] = 0.f;
    const float* wrow = W_out + (size_t)l * HID;
    for (int e = 0; e < HID; e += 4) {
        float4 wv = *(const float4*)(wrow + e);
#pragma unroll
        for (int r = 0; r < 8; r++) {
            float4 hv = *(const float4*)&hl[r * HID + e];
            acc[r] += wv.x * hv.x + wv.y * hv.y + wv.z * hv.z + wv.w * hv.w;
        }
    }
    const float bo = b_out[l];
#pragma unroll
    for (int r = 0; r < 8; r++) {
        float v = acc[r] + bo;
        float mx = v;
#pragma unroll
        for (int m = 32; m >= 1; m >>= 1) mx = fmaxf(mx, __shfl_xor(mx, m));
        float ex = __expf(v - mx);
        float sm = ex;
#pragma unroll
        for (int m = 32; m >= 1; m >>= 1) sm += __shfl_xor(sm, m);
        out[(size_t)(b * 8 + r) * NTAGS + l] = v - mx - __logf(sm);
    }
}

extern "C" void kernel_launch(void* const* d_in, const int* in_sizes, int n_in,
                              void* d_out, int out_size, void* d_ws, size_t ws_size,
                              hipStream_t stream) {
    const int* sent = (const int*)d_in[0];
    const float* emb = (const float*)d_in[1];
    const float* W_ih = (const float*)d_in[2];
    const float* W_hh = (const float*)d_in[3];
    const float* b_ih = (const float*)d_in[4];
    const float* b_hh = (const float*)d_in[5];
    const float* W_out = (const float*)d_in[6];
    const float* b_out = (const float*)d_in[7];
    float* out = (float*)d_out;

    char* ws = (char*)d_ws;
    float* xp = (float*)ws;                                   // 64 MB
    float* hs = (float*)(ws + ((size_t)64 << 20));            // 16 MB
    float* bsum = (float*)(ws + ((size_t)80 << 20));          // 16 KB
    float* hbuf = (float*)(ws + ((size_t)80 << 20) + 16384);  // 8 KB
    int* flags = (int*)(ws + ((size_t)80 << 20) + 16384 + 8192);

    prep_kernel<<<16, 256, 0, stream>>>(b_ih, b_hh, bsum, hbuf, flags);
    dim3 g(G4H / 64, T_LEN / 64);
    xproj_gemm<<<g, 256, 0, stream>>>(sent, emb, W_ih, bsum, xp);
    lstm_scan<<<NWG, 256, 0, stream>>>(W_hh, xp, hbuf, flags, hs);
    out_kernel<<<512, 64, 0, stream>>>(hs, W_out, b_out, out);
}

// Round 2
// 15298.640 us; speedup vs baseline: 5.7233x; 5.7233x over previous
//
#include <hip/hip_runtime.h>
#include <hip/hip_bf16.h>

// LSTM tagger: T=4096, V=50257, E=512, H=1024, TAGS=64
//
//   K1 prep:   bsum = b_ih + b_hh; init (h,tag) pair buffers.
//   K2 gemm:   x_proj[T][4H] = emb[sentence] @ W_ih^T + bsum   (fp32 tiled)
//   K3 scan:   persistent 128 WGs x 256 thr. WG g owns h[8g..8g+8), wave w
//              owns entries j0=8g+2w, j0+1. W_hh slice in VGPRs (128/thread).
//              Sync: fused 64-bit (tag<<32|h) pairs, RELAXED agent atomics
//              only (no acquire/release -> no L2 wbinv storms). Each wave
//              polls a 256-entry quarter, stages to LDS, one barrier/step.
//   K4 out:    tag_space = hs @ W_out^T + b_out; log_softmax over 64 tags.

#define T_LEN 4096
#define HID   1024
#define G4H   4096
#define EMBD  512
#define NTAGS 64
#define NWG_SCAN 128

__device__ __forceinline__ float fast_sig(float x) {
    return 1.f / (1.f + __expf(-x));
}
__device__ __forceinline__ float fast_tanh(float x) {
    x = fminf(15.f, fmaxf(-15.f, x));
    float e = __expf(2.f * x);
    return (e - 1.f) / (e + 1.f);
}

__global__ void prep_kernel(const float* __restrict__ b_ih, const float* __restrict__ b_hh,
                            float* __restrict__ bsum, unsigned long long* __restrict__ pairs) {
    int i = blockIdx.x * blockDim.x + threadIdx.x;
    int n = gridDim.x * blockDim.x;
    for (int k = i; k < G4H; k += n) bsum[k] = b_ih[k] + b_hh[k];
    for (int k = i; k < HID; k += n) {
        pairs[k] = 0ULL;                          // parity 0: tag=0, h=0.0f
        pairs[HID + k] = 0xFFFFFFFF00000000ULL;   // parity 1: invalid tag
    }
}

// C[m,n] = sum_k emb[sent[m]][k] * W_ih[n][k] + bsum[n]; 64x64 tile per WG.
__global__ __launch_bounds__(256) void xproj_gemm(const int* __restrict__ sent,
                                                  const float* __restrict__ emb,
                                                  const float* __restrict__ W_ih,
                                                  const float* __restrict__ bsum,
                                                  float* __restrict__ xp) {
    __shared__ float As[32][68];
    __shared__ float Bs[32][68];
    const int tid = threadIdx.x;
    const int bx = blockIdx.x;  // n tile
    const int by = blockIdx.y;  // m tile
    const int tx = tid & 15, ty = tid >> 4;
    const int mrow = tid >> 2;     // 0..63
    const int kq = (tid & 3) * 8;  // 0,8,16,24

    float acc[4][4];
#pragma unroll
    for (int r = 0; r < 4; r++)
#pragma unroll
        for (int c = 0; c < 4; c++) acc[r][c] = 0.f;

    const int sid = sent[by * 64 + mrow];
    const float* arow = emb + (size_t)sid * EMBD;
    const float* brow = W_ih + (size_t)(bx * 64 + mrow) * EMBD;

    for (int kk = 0; kk < EMBD; kk += 32) {
        float4 a0 = *(const float4*)(arow + kk + kq);
        float4 a1 = *(const float4*)(arow + kk + kq + 4);
        float4 b0 = *(const float4*)(brow + kk + kq);
        float4 b1 = *(const float4*)(brow + kk + kq + 4);
        __syncthreads();
        const float* ap0 = (const float*)&a0;
        const float* ap1 = (const float*)&a1;
        const float* bp0 = (const float*)&b0;
        const float* bp1 = (const float*)&b1;
#pragma unroll
        for (int r = 0; r < 4; r++) {
            As[kq + r][mrow] = ap0[r];
            As[kq + 4 + r][mrow] = ap1[r];
            Bs[kq + r][mrow] = bp0[r];
            Bs[kq + 4 + r][mrow] = bp1[r];
        }
        __syncthreads();
#pragma unroll
        for (int k = 0; k < 32; k++) {
            float4 av = *(const float4*)&As[k][ty * 4];
            float4 bv = *(const float4*)&Bs[k][tx * 4];
            const float* ar = (const float*)&av;
            const float* br = (const float*)&bv;
#pragma unroll
            for (int r = 0; r < 4; r++)
#pragma unroll
                for (int c = 0; c < 4; c++) acc[r][c] = fmaf(ar[r], br[c], acc[r][c]);
        }
    }
    const int crow = by * 64 + ty * 4;
    const int ccol = bx * 64 + tx * 4;
    float bs[4];
#pragma unroll
    for (int c = 0; c < 4; c++) bs[c] = bsum[ccol + c];
#pragma unroll
    for (int r = 0; r < 4; r++) {
        float4 v;
        v.x = acc[r][0] + bs[0];
        v.y = acc[r][1] + bs[1];
        v.z = acc[r][2] + bs[2];
        v.w = acc[r][3] + bs[3];
        *(float4*)&xp[(size_t)(crow + r) * G4H + ccol] = v;
    }
}

// Persistent recurrent scan. 128 WGs x 256 threads; WG g owns h[8g..8g+8).
// Wave w owns entries j0 = 8g+2w, j0+1; lane l covers cols {k*64+l}.
// Publication: pairs[par][j] = ((u64)step << 32) | f32bits(h), relaxed agent
// atomics ONLY. Exact tag match (==t) prevents ABA; the dense dependency
// h_{s-1} -> h_s guarantees no slot is overwritten before all consumers'
// loads of the previous value have returned.
__global__ __launch_bounds__(256, 1) void lstm_scan(const float* __restrict__ W_hh,
                                                    const float* __restrict__ xp,
                                                    unsigned long long* __restrict__ pairs,
                                                    float* __restrict__ hs) {
    __shared__ float h_lds[2][HID];
    const int tid = threadIdx.x;
    const int g = blockIdx.x;
    const int w = tid >> 6;
    const int l = tid & 63;
    const int j0 = g * 8 + w * 2;

    // wreg[e][q][k] = W_hh[(q*H + j0+e)][k*64 + l]
    float wreg[2][4][16];
#pragma unroll
    for (int e = 0; e < 2; e++)
#pragma unroll
        for (int q = 0; q < 4; q++) {
            const float* wr = W_hh + (size_t)(q * HID + j0 + e) * HID + l;
#pragma unroll
            for (int k = 0; k < 16; k++) wreg[e][q][k] = wr[k * 64];
        }

    float c0 = 0.f, c1 = 0.f;
    for (int s = 1; s <= T_LEN; ++s) {
        const int t = s - 1;
        const unsigned need = (unsigned)t;

        // prefetch gate biases for this step (off critical path)
        float xpv[2][4];
        if (l == 0) {
#pragma unroll
            for (int e = 0; e < 2; e++)
#pragma unroll
                for (int q = 0; q < 4; q++)
                    xpv[e][q] = xp[(size_t)t * G4H + q * HID + j0 + e];
        }

        // poll own quarter: 4 fused pairs per lane, relaxed (no cache maint.)
        const unsigned long long* pp = pairs + (size_t)(t & 1) * HID + w * 256 + l;
        unsigned long long v0, v1, v2, v3;
        for (;;) {
            v0 = __hip_atomic_load(pp + 0, __ATOMIC_RELAXED, __HIP_MEMORY_SCOPE_AGENT);
            v1 = __hip_atomic_load(pp + 64, __ATOMIC_RELAXED, __HIP_MEMORY_SCOPE_AGENT);
            v2 = __hip_atomic_load(pp + 128, __ATOMIC_RELAXED, __HIP_MEMORY_SCOPE_AGENT);
            v3 = __hip_atomic_load(pp + 192, __ATOMIC_RELAXED, __HIP_MEMORY_SCOPE_AGENT);
            bool ok = ((unsigned)(v0 >> 32) == need) && ((unsigned)(v1 >> 32) == need) &&
                      ((unsigned)(v2 >> 32) == need) && ((unsigned)(v3 >> 32) == need);
            if (__all(ok)) break;
            __builtin_amdgcn_s_sleep(1);
        }
        float* hq = h_lds[t & 1] + w * 256 + l;
        hq[0] = __uint_as_float((unsigned)v0);
        hq[64] = __uint_as_float((unsigned)v1);
        hq[128] = __uint_as_float((unsigned)v2);
        hq[192] = __uint_as_float((unsigned)v3);
        __syncthreads();  // h_{t} staged; LDS parity double-buffer makes 1 barrier safe

        float a[2][4];
#pragma unroll
        for (int e = 0; e < 2; e++)
#pragma unroll
            for (int q = 0; q < 4; q++) a[e][q] = 0.f;
        const float* hb = h_lds[t & 1];
#pragma unroll
        for (int k = 0; k < 16; k++) {
            float hv = hb[k * 64 + l];
#pragma unroll
            for (int e = 0; e < 2; e++)
#pragma unroll
                for (int q = 0; q < 4; q++)
                    a[e][q] = fmaf(wreg[e][q][k], hv, a[e][q]);
        }
#pragma unroll
        for (int m = 32; m >= 1; m >>= 1) {
#pragma unroll
            for (int e = 0; e < 2; e++)
#pragma unroll
                for (int q = 0; q < 4; q++) a[e][q] += __shfl_xor(a[e][q], m);
        }

        if (l == 0) {
            float si0 = fast_sig(a[0][0] + xpv[0][0]);
            float sf0 = fast_sig(a[0][1] + xpv[0][1]);
            float tg0 = fast_tanh(a[0][2] + xpv[0][2]);
            float so0 = fast_sig(a[0][3] + xpv[0][3]);
            c0 = sf0 * c0 + si0 * tg0;
            float hv0 = so0 * fast_tanh(c0);

            float si1 = fast_sig(a[1][0] + xpv[1][0]);
            float sf1 = fast_sig(a[1][1] + xpv[1][1]);
            float tg1 = fast_tanh(a[1][2] + xpv[1][2]);
            float so1 = fast_sig(a[1][3] + xpv[1][3]);
            c1 = sf1 * c1 + si1 * tg1;
            float hv1 = so1 * fast_tanh(c1);

            unsigned long long p0 =
                ((unsigned long long)(unsigned)s << 32) | (unsigned long long)__float_as_uint(hv0);
            unsigned long long p1 =
                ((unsigned long long)(unsigned)s << 32) | (unsigned long long)__float_as_uint(hv1);
            unsigned long long* dst = pairs + (size_t)(s & 1) * HID + j0;
            __hip_atomic_store(dst + 0, p0, __ATOMIC_RELAXED, __HIP_MEMORY_SCOPE_AGENT);
            __hip_atomic_store(dst + 1, p1, __ATOMIC_RELAXED, __HIP_MEMORY_SCOPE_AGENT);
            hs[(size_t)t * HID + j0] = hv0;
            hs[(size_t)t * HID + j0 + 1] = hv1;
        }
    }
}

// tag_space = hs @ W_out^T + b_out; log_softmax per row. 8 rows per WG, 1 wave.
__global__ __launch_bounds__(64) void out_kernel(const float* __restrict__ hs,
                                                 const float* __restrict__ W_out,
                                                 const float* __restrict__ b_out,
                                                 float* __restrict__ out) {
    __shared__ float hl[8 * HID];
    const int l = threadIdx.x;
    const int b = blockIdx.x;  // 512 blocks
    const float* hr = hs + (size_t)b * 8 * HID;
#pragma unroll
    for (int jj = 0; jj < 32; jj++) {
        int f4 = l + 64 * jj;
        ((float4*)hl)[f4] = ((const float4*)hr)[f4];
    }
    __syncthreads();
    float acc[8];
#pragma unroll
    for (int r = 0; r < 8; r++) acc[r] = 0.f;
    const float* wrow = W_out + (size_t)l * HID;
    for (int e = 0; e < HID; e += 4) {
        float4 wv = *(const float4*)(wrow + e);
#pragma unroll
        for (int r = 0; r < 8; r++) {
            float4 hv = *(const float4*)&hl[r * HID + e];
            acc[r] += wv.x * hv.x + wv.y * hv.y + wv.z * hv.z + wv.w * hv.w;
        }
    }
    const float bo = b_out[l];
#pragma unroll
    for (int r = 0; r < 8; r++) {
        float v = acc[r] + bo;
        float mx = v;
#pragma unroll
        for (int m = 32; m >= 1; m >>= 1) mx = fmaxf(mx, __shfl_xor(mx, m));
        float ex = __expf(v - mx);
        float sm = ex;
#pragma unroll
        for (int m = 32; m >= 1; m >>= 1) sm += __shfl_xor(sm, m);
        out[(size_t)(b * 8 + r) * NTAGS + l] = v - mx - __logf(sm);
    }
}

extern "C" void kernel_launch(void* const* d_in, const int* in_sizes, int n_in,
                              void* d_out, int out_size, void* d_ws, size_t ws_size,
                              hipStream_t stream) {
    const int* sent = (const int*)d_in[0];
    const float* emb = (const float*)d_in[1];
    const float* W_ih = (const float*)d_in[2];
    const float* W_hh = (const float*)d_in[3];
    const float* b_ih = (const float*)d_in[4];
    const float* b_hh = (const float*)d_in[5];
    const float* W_out = (const float*)d_in[6];
    const float* b_out = (const float*)d_in[7];
    float* out = (float*)d_out;

    char* ws = (char*)d_ws;
    float* xp = (float*)ws;                                     // 64 MB
    float* hs = (float*)(ws + ((size_t)64 << 20));              // 16 MB
    unsigned long long* pairs =
        (unsigned long long*)(ws + ((size_t)80 << 20));         // 16 KB
    float* bsum = (float*)(ws + ((size_t)80 << 20) + 32768);    // 16 KB

    prep_kernel<<<16, 256, 0, stream>>>(b_ih, b_hh, bsum, pairs);
    dim3 g(G4H / 64, T_LEN / 64);
    xproj_gemm<<<g, 256, 0, stream>>>(sent, emb, W_ih, bsum, xp);
    lstm_scan<<<NWG_SCAN, 256, 0, stream>>>(W_hh, xp, pairs, hs);
    out_kernel<<<512, 64, 0, stream>>>(hs, W_out, b_out, out);
}